// Round 5
// baseline (328.230 us; speedup 1.0000x reference)
//
#include <hip/hip_runtime.h>
#include <hip/hip_bf16.h>
#include <stdint.h>

typedef short bf16x8 __attribute__((ext_vector_type(8)));
typedef float f32x4 __attribute__((ext_vector_type(4)));
typedef unsigned int u32x4 __attribute__((ext_vector_type(4)));

__device__ __forceinline__ uint32_t pack2f(float lo, float hi) {
  union { __hip_bfloat162 h; uint32_t u; } c;
  c.h.x = __float2bfloat16(lo);
  c.h.y = __float2bfloat16(hi);
  return c.u;
}

__device__ __forceinline__ u32x4 packchunk(f32x4 p, f32x4 q) {
  u32x4 r;
  r.x = pack2f(p.x, p.y);
  r.y = pack2f(p.z, p.w);
  r.z = pack2f(q.x, q.y);
  r.w = pack2f(q.z, q.w);
  return r;
}

__device__ __forceinline__ unsigned short f32_to_bf16(float f) {
  union { __hip_bfloat16 h; unsigned short u; } c;
  c.h = __float2bfloat16(f);
  return c.u;
}

__device__ __forceinline__ float fast_tanh(float x) {
  float e = __builtin_amdgcn_exp2f(x * 2.8853900817779268f);
  return 1.0f - 2.0f * __builtin_amdgcn_rcpf(e + 1.0f);
}

// ---------------- W1k transpose + bf16 convert; also zeroes ctx_pre ----------------
__global__ void transpose_w1k(const float* __restrict__ W1, unsigned short* __restrict__ W1kt,
                              float* __restrict__ ctx_pre) {
  __shared__ float t[64][65];
  const int kb = blockIdx.x * 64;
  const int jb = blockIdx.y * 64;
  const int c = threadIdx.x & 63;
  const int r = threadIdx.x >> 6;  // 0..3
  const int gid = (blockIdx.y * 16 + blockIdx.x) * 256 + threadIdx.x;
  if (gid < 16384) ctx_pre[gid] = 0.f;
#pragma unroll
  for (int i = 0; i < 16; ++i) {
    const int k = i * 4 + r;
    t[k][c] = W1[(size_t)(1024 + kb + k) * 1024 + (jb + c)];
  }
  __syncthreads();
#pragma unroll
  for (int i = 0; i < 16; ++i) {
    const int j = i * 4 + r;
    W1kt[(size_t)(jb + j) * 1024 + (kb + c)] = f32_to_bf16(t[c][j]);
  }
}

// ---------------- qterm[b][j] = b1[j] + sum_k query[b][k]*W1[k][j] ----------------
__global__ void qterm_kernel(const float* __restrict__ query, const float* __restrict__ W1,
                             const float* __restrict__ b1, float* __restrict__ qterm) {
  const int b = blockIdx.y;
  const int j = blockIdx.x * 256 + threadIdx.x;
  const float* q = query + b * 1024;
  float acc = b1[j];
#pragma unroll 8
  for (int k = 0; k < 1024; ++k) acc += q[k] * W1[(size_t)k * 1024 + j];
  qterm[b * 1024 + j] = acc;
}

// ---------------- fused GEMM + tanh + W2-reduce ----------------
// 256 threads / 4 waves per block; block = 64 rows x 256 cols; grid 2048.
// 4 blocks/CU (128 regs, 32KB LDS each) -> decorrelated barriers.
// A tile [64][128] bf16 in LDS, double-buffered, byte ^= ((row&7)<<4) swizzle.
// B (W1kt) read per-wave from L2. Partial scores -> scores_part[colgrp][32768].
#define MFMA16(a, b, c) __builtin_amdgcn_mfma_f32_16x16x32_bf16(a, b, c, 0, 0, 0)

#define KSTEP(ks)                                                                            \
  {                                                                                          \
    bf16x8 af[4];                                                                            \
    _Pragma("unroll") for (int mf = 0; mf < 4; ++mf) af[mf] =                                \
        *(const bf16x8*)(Ac + (mf * 16 + c16) * 256 + (((ks) * 64 + q4 * 16) ^ swzr));       \
    bf16x8 bv[4];                                                                            \
    _Pragma("unroll") for (int ni = 0; ni < 4; ++ni) bv[ni] =                                \
        *(const bf16x8*)(gB + (size_t)ni * 16384 + kt * 128 + (ks) * 32);                    \
    _Pragma("unroll") for (int ni = 0; ni < 4; ++ni)                                         \
        _Pragma("unroll") for (int mf = 0; mf < 4; ++mf) acc[ni][mf] =                       \
            MFMA16(af[mf], bv[ni], acc[ni][mf]);                                             \
  }

__global__ __launch_bounds__(256, 4) void gemm_score_kernel(
    const float* __restrict__ keys, const unsigned short* __restrict__ W1kt,
    const float* __restrict__ qterm, const float* __restrict__ coverage,
    const float* __restrict__ W1, const float* __restrict__ W2,
    float* __restrict__ scores_part) {
  __shared__ __align__(16) unsigned char Ab[2][16384];
  const int tid = threadIdx.x;
  // bijective XCD swizzle: 4 col-blocks of one row-group land on one XCD
  const int phys = blockIdx.x;  // 0..2047
  const int xcd = phys & 7;
  const int idx = phys >> 3;             // 0..255
  const int rowgrp = xcd * 64 + (idx >> 2);  // 0..511
  const int colgrp = idx & 3;
  const int row0 = rowgrp * 64;
  const int col0 = colgrp * 256;
  const int b = row0 >> 11;  // 2048 rows per batch
  const int w = tid >> 6;    // 0..3
  const int lane = tid & 63;
  const int c16 = lane & 15;
  const int q4 = lane >> 4;

  // staging: 4 threads per row, 32 fp32 each per kt (two 16-float groups)
  const int srow = tid >> 2;
  const int sk4 = (tid & 3) * 32;
  const float* gA = keys + (size_t)(row0 + srow) * 1024 + sk4;
  const int swzw = (srow & 7) << 4;
  const int wofA0 = srow * 256 + ((sk4 * 2) ^ swzw);
  const int wofA1 = srow * 256 + ((sk4 * 2 + 16) ^ swzw);
  const int wofB0 = srow * 256 + ((sk4 * 2 + 32) ^ swzw);
  const int wofB1 = srow * 256 + ((sk4 * 2 + 48) ^ swzw);

  const int swzr = (c16 & 7) << 4;
  const unsigned short* gB = W1kt + (size_t)(col0 + w * 64 + c16) * 1024 + q4 * 8;

  f32x4 acc[4][4];  // [ni][mf]
  const f32x4 zz = {0.f, 0.f, 0.f, 0.f};
#pragma unroll
  for (int ni = 0; ni < 4; ++ni)
#pragma unroll
    for (int mf = 0; mf < 4; ++mf) acc[ni][mf] = zz;

  // prologue: stage kt=0 into buf 0
  {
    f32x4 a0 = *(const f32x4*)(gA + 0), a1 = *(const f32x4*)(gA + 4);
    f32x4 a2 = *(const f32x4*)(gA + 8), a3 = *(const f32x4*)(gA + 12);
    f32x4 b0 = *(const f32x4*)(gA + 16), b1v = *(const f32x4*)(gA + 20);
    f32x4 b2 = *(const f32x4*)(gA + 24), b3 = *(const f32x4*)(gA + 28);
    *(u32x4*)(Ab[0] + wofA0) = packchunk(a0, a1);
    *(u32x4*)(Ab[0] + wofA1) = packchunk(a2, a3);
    *(u32x4*)(Ab[0] + wofB0) = packchunk(b0, b1v);
    *(u32x4*)(Ab[0] + wofB1) = packchunk(b2, b3);
  }
  __syncthreads();

#pragma unroll
  for (int kt = 0; kt < 8; ++kt) {
    const unsigned char* Ac = Ab[kt & 1];
    unsigned char* An = Ab[(kt + 1) & 1];
    f32x4 sa0, sa1, sa2, sa3;
    if (kt < 7) {  // issue-early: group A loads for kt+1
      const float* g = gA + (kt + 1) * 128;
      sa0 = *(const f32x4*)(g + 0);
      sa1 = *(const f32x4*)(g + 4);
      sa2 = *(const f32x4*)(g + 8);
      sa3 = *(const f32x4*)(g + 12);
    }
    KSTEP(0)
    KSTEP(1)
    f32x4 sb0, sb1, sb2, sb3;
    if (kt < 7) {  // write-late group A; issue group B
      *(u32x4*)(An + wofA0) = packchunk(sa0, sa1);
      *(u32x4*)(An + wofA1) = packchunk(sa2, sa3);
      const float* g = gA + (kt + 1) * 128;
      sb0 = *(const f32x4*)(g + 16);
      sb1 = *(const f32x4*)(g + 20);
      sb2 = *(const f32x4*)(g + 24);
      sb3 = *(const f32x4*)(g + 28);
    }
    KSTEP(2)
    KSTEP(3)
    if (kt < 7) {
      *(u32x4*)(An + wofB0) = packchunk(sb0, sb1);
      *(u32x4*)(An + wofB1) = packchunk(sb2, sb3);
    }
    __syncthreads();
  }

  // epilogue: v = acc + qterm + cov*W1c; p_part = sum_j tanh(v)*W2[j]
  float covv[4][4];
#pragma unroll
  for (int mf = 0; mf < 4; ++mf)
#pragma unroll
    for (int r = 0; r < 4; ++r) covv[mf][r] = coverage[row0 + mf * 16 + q4 * 4 + r];

  float p_part[4][4];
#pragma unroll
  for (int mf = 0; mf < 4; ++mf)
#pragma unroll
    for (int r = 0; r < 4; ++r) p_part[mf][r] = 0.f;

#pragma unroll
  for (int ni = 0; ni < 4; ++ni) {
    const int col = col0 + w * 64 + ni * 16 + c16;
    const float qt = qterm[b * 1024 + col];
    const float w1c = W1[(size_t)2048 * 1024 + col];
    const float w2 = W2[col];
#pragma unroll
    for (int mf = 0; mf < 4; ++mf)
#pragma unroll
      for (int r = 0; r < 4; ++r) {
        float v = acc[ni][mf][r] + qt + covv[mf][r] * w1c;
        p_part[mf][r] += fast_tanh(v) * w2;
      }
  }

  // reduce: shfl over 16 col-lanes, then cross-wave via LDS (overlaid on Ab;
  // safe: barrier at end of kt=7 means all A reads are done)
  float* Sred = (float*)Ab;  // [4][64]
#pragma unroll
  for (int mf = 0; mf < 4; ++mf)
#pragma unroll
    for (int r = 0; r < 4; ++r) {
      float p = p_part[mf][r];
      p += __shfl_xor(p, 1);
      p += __shfl_xor(p, 2);
      p += __shfl_xor(p, 4);
      p += __shfl_xor(p, 8);
      if (c16 == 0) Sred[w * 64 + mf * 16 + q4 * 4 + r] = p;
    }
  __syncthreads();
  if (tid < 64) {
    float s = Sred[tid] + Sred[64 + tid] + Sred[128 + tid] + Sred[192 + tid];
    scores_part[(size_t)colgrp * 32768 + row0 + tid] = s;  // plain store, deterministic
  }
}

// ---------------- softmax over L per batch (sums 4 col-group partials) ----------------
__global__ void softmax_kernel(const float* __restrict__ sp, float* __restrict__ att) {
  const int b = blockIdx.x;
  const int tid = threadIdx.x;
  const float* s = sp + b * 2048;
  float* a = att + b * 2048;
  __shared__ float red[4];
  float mx = -1e30f;
  for (int l = tid; l < 2048; l += 256) {
    float v = s[l] + s[l + 32768] + s[l + 65536] + s[l + 98304];
    a[l] = v;
    mx = fmaxf(mx, v);
  }
#pragma unroll
  for (int o = 1; o < 64; o <<= 1) mx = fmaxf(mx, __shfl_xor(mx, o));
  if ((tid & 63) == 0) red[tid >> 6] = mx;
  __syncthreads();
  mx = fmaxf(fmaxf(red[0], red[1]), fmaxf(red[2], red[3]));
  __syncthreads();
  float sum = 0.f;
  for (int l = tid; l < 2048; l += 256) {
    float e = __expf(a[l] - mx);
    a[l] = e;
    sum += e;
  }
#pragma unroll
  for (int o = 1; o < 64; o <<= 1) sum += __shfl_xor(sum, o);
  if ((tid & 63) == 0) red[tid >> 6] = sum;
  __syncthreads();
  sum = red[0] + red[1] + red[2] + red[3];
  const float inv = 1.0f / sum;
  for (int l = tid; l < 2048; l += 256) a[l] *= inv;
}

// ---------------- ctx_pre[b][j] = sum_l att[b][l] * keys[b][l][j] ----------------
__global__ void ctxpre_kernel(const float* __restrict__ keys, const float* __restrict__ att,
                              float* __restrict__ ctx_pre) {
  const int b = blockIdx.x;   // 16
  const int sl = blockIdx.y;  // 32 slices of 64 rows
  const int tid = threadIdx.x;
  const float* ab = att + b * 2048 + sl * 64;
  const f32x4* kb = (const f32x4*)(keys + ((size_t)b * 2048 + sl * 64) * 1024) + tid;
  f32x4 acc = {0.f, 0.f, 0.f, 0.f};
#pragma unroll 4
  for (int l = 0; l < 64; ++l) acc += kb[(size_t)l * 256] * ab[l];
  float* cp = ctx_pre + b * 1024 + tid * 4;
  atomicAdd(cp + 0, acc.x);
  atomicAdd(cp + 1, acc.y);
  atomicAdd(cp + 2, acc.z);
  atomicAdd(cp + 3, acc.w);
}

// ---------------- context[b][h] = sum_j ctx_pre[b][j] * Wr[j][h] ----------------
__global__ void context_kernel(const float* __restrict__ ctx_pre, const float* __restrict__ Wr,
                               float* __restrict__ out) {
  const int b = blockIdx.y;
  const int h = blockIdx.x * 256 + threadIdx.x;
  const float* cp = ctx_pre + b * 1024;
  float acc = 0.f;
#pragma unroll 8
  for (int j = 0; j < 1024; ++j) acc += cp[j] * Wr[(size_t)j * 512 + h];
  out[b * 512 + h] = acc;
}

extern "C" void kernel_launch(void* const* d_in, const int* in_sizes, int n_in, void* d_out,
                              int out_size, void* d_ws, size_t ws_size, hipStream_t stream) {
  const float* query = (const float*)d_in[0];     // (16,1,1024)
  const float* keys = (const float*)d_in[1];      // (16,2048,1024)
  const float* coverage = (const float*)d_in[2];  // (16,2048,1)
  const float* W1 = (const float*)d_in[3];        // (2049,1024)
  const float* b1 = (const float*)d_in[4];        // (1024,)
  const float* W2 = (const float*)d_in[5];        // (1024,1)
  const float* Wr = (const float*)d_in[6];        // (1024,512)
  float* out = (float*)d_out;
  char* ws = (char*)d_ws;

  float* scores_part = (float*)ws;                        // 4*32768 f32 (512KB)
  float* ctx_pre = (float*)(ws + 524288);                 // 16384 f32
  float* qterm = (float*)(ws + 589824);                   // 16384 f32
  unsigned short* W1kt = (unsigned short*)(ws + 655360);  // 1M bf16 (2MB)

  float* context_out = out;     // 16*512
  float* att_out = out + 8192;  // 16*2048

  transpose_w1k<<<dim3(16, 16), dim3(256), 0, stream>>>(W1, W1kt, ctx_pre);
  qterm_kernel<<<dim3(4, 16), dim3(256), 0, stream>>>(query, W1, b1, qterm);
  gemm_score_kernel<<<dim3(2048), dim3(256), 0, stream>>>(keys, W1kt, qterm, coverage, W1, W2,
                                                          scores_part);
  softmax_kernel<<<dim3(16), dim3(256), 0, stream>>>(scores_part, att_out);
  ctxpre_kernel<<<dim3(16, 32), dim3(256), 0, stream>>>(keys, att_out, ctx_pre);
  context_kernel<<<dim3(2, 16), dim3(256), 0, stream>>>(ctx_pre, Wr, context_out);
}

// Round 6
// 228.575 us; speedup vs baseline: 1.4360x; 1.4360x over previous
//
#include <hip/hip_runtime.h>
#include <hip/hip_bf16.h>
#include <stdint.h>

typedef short bf16x8 __attribute__((ext_vector_type(8)));
typedef float f32x4 __attribute__((ext_vector_type(4)));
typedef unsigned int u32x2 __attribute__((ext_vector_type(2)));

__device__ __forceinline__ uint32_t pack2f(float lo, float hi) {
  union { __hip_bfloat162 h; uint32_t u; } c;
  c.h.x = __float2bfloat16(lo);
  c.h.y = __float2bfloat16(hi);
  return c.u;
}

__device__ __forceinline__ unsigned short f32_to_bf16(float f) {
  union { __hip_bfloat16 h; unsigned short u; } c;
  c.h = __float2bfloat16(f);
  return c.u;
}

__device__ __forceinline__ float bf16_to_f32(short s) {
  union { uint32_t u; float f; } c;
  c.u = ((uint32_t)(unsigned short)s) << 16;
  return c.f;
}

__device__ __forceinline__ float fast_tanh(float x) {
  float e = __builtin_amdgcn_exp2f(x * 2.8853900817779268f);
  return 1.0f - 2.0f * __builtin_amdgcn_rcpf(e + 1.0f);
}

#define GLD16(g, l)                                                                    \
  __builtin_amdgcn_global_load_lds((const __attribute__((address_space(1))) void*)(g), \
                                   (__attribute__((address_space(3))) void*)(l), 16, 0, 0)

// ---------------- W1k transpose + bf16 convert: W1kt[j][k] = bf16(W1[1024+k][j]) ----------------
__global__ void transpose_w1k(const float* __restrict__ W1, unsigned short* __restrict__ W1kt) {
  __shared__ float t[64][65];
  const int kb = blockIdx.x * 64;
  const int jb = blockIdx.y * 64;
  const int c = threadIdx.x & 63;
  const int r = threadIdx.x >> 6;  // 0..3
#pragma unroll
  for (int i = 0; i < 16; ++i) {
    const int k = i * 4 + r;
    t[k][c] = W1[(size_t)(1024 + kb + k) * 1024 + (jb + c)];
  }
  __syncthreads();
#pragma unroll
  for (int i = 0; i < 16; ++i) {
    const int j = i * 4 + r;
    W1kt[(size_t)(jb + j) * 1024 + (kb + c)] = f32_to_bf16(t[c][j]);
  }
}

// ---------------- qterm[b][j] = b1[j] + sum_k query[b][k]*W1[k][j] ----------------
__global__ void qterm_kernel(const float* __restrict__ query, const float* __restrict__ W1,
                             const float* __restrict__ b1, float* __restrict__ qterm) {
  const int b = blockIdx.y;
  const int j = blockIdx.x * 256 + threadIdx.x;
  const float* q = query + b * 1024;
  float acc = b1[j];
#pragma unroll 8
  for (int k = 0; k < 1024; ++k) acc += q[k] * W1[(size_t)k * 1024 + j];
  qterm[b * 1024 + j] = acc;
}

// ---------------- fused GEMM + tanh + W2-reduce (m97 structure) ----------------
// 256 thr / 4 waves (2x2 of 64x64), tile 128x128, BK=64, grid 2048.
// B: global_load_lds, swizzle folded into per-lane global src (linear LDS dest).
// A: fp32 reg-staged -> bf16 pack -> swizzled ds_write_b64.
// LDS unit-swizzle: 16B unit u of row r stored at unit (u ^ (r&7)).
#define MFMA16(a, b, c) __builtin_amdgcn_mfma_f32_16x16x32_bf16(a, b, c, 0, 0, 0)

__global__ __launch_bounds__(256, 3) void gemm_score_kernel(
    const float* __restrict__ keys, const unsigned short* __restrict__ W1kt,
    const float* __restrict__ qterm, const float* __restrict__ coverage,
    const float* __restrict__ W1, const float* __restrict__ W2,
    float* __restrict__ scores_part) {
  __shared__ __align__(16) unsigned char lds[33792];
  unsigned char* Alds = lds;            // 16KB: 128 rows x 128B
  unsigned char* Blds = lds + 16384;    // 16KB: 128 cols x 128B
  float* Sred = (float*)(lds + 32768);  // 4 x 64 f32

  const int tid = threadIdx.x;
  const int bid = blockIdx.x;
  // bijective XCD clustering: XCD x handles rowgrps [32x,32x+32), all 8 colgrps
  const int xcd = bid & 7;
  const int idx = bid >> 3;                  // 0..255
  const int rowgrp = xcd * 32 + (idx >> 3);  // 0..255
  const int colgrp = idx & 7;                // 0..7
  const int row0 = rowgrp * 128;
  const int col0 = colgrp * 128;
  const int b = row0 >> 11;
  const int w = tid >> 6;
  const int wm = w >> 1, wn = w & 1;
  const int lane = tid & 63;
  const int c16 = lane & 15, q4 = lane >> 4;

  // ---- A staging map: thread t covers rows (t>>4)+j*16 (j=0..7), k-floats (t&15)*4 ----
  const int arow = tid >> 4;        // base row
  const int akf = (tid & 15) * 4;   // k-float offset within tile
  const float* gA = keys + (size_t)(row0 + arow) * 1024 + akf;
  // ds_write addr per j: r = arow + j*16; byte = r*128 + ((((t&15)>>1) ^ (r&7))<<4) + (t&1)*8
  const int auh = (tid & 1) * 8;
  const int aun = (tid & 15) >> 1;

  // ---- B staging map (global_load_lds): call i: lane covers LDS row r=w*32+i*8+(lane>>3),
  //      unit u=lane&7; global src unit = u ^ (r&7) ----
  const unsigned char* ldsB_dst = Blds + w * 4096 + lane * 16;

  f32x4 acc[4][4];  // [mf][nf]
  const f32x4 zz = {0.f, 0.f, 0.f, 0.f};
#pragma unroll
  for (int mf = 0; mf < 4; ++mf)
#pragma unroll
    for (int nf = 0; nf < 4; ++nf) acc[mf][nf] = zz;

  // prologue: load A(0)
  f32x4 Ar[8];
#pragma unroll
  for (int j = 0; j < 8; ++j) Ar[j] = *(const f32x4*)(gA + (size_t)j * 16 * 1024);

  for (int kt = 0; kt < 16; ++kt) {
    if (kt) __syncthreads();  // (a) previous compute done; buffers free
    // ds_write A(kt)
#pragma unroll
    for (int j = 0; j < 8; ++j) {
      const int r = arow + j * 16;
      u32x2 p;
      p.x = pack2f(Ar[j].x, Ar[j].y);
      p.y = pack2f(Ar[j].z, Ar[j].w);
      *(u32x2*)(Alds + r * 128 + (((aun ^ (r & 7)) << 4) + auh)) = p;
    }
    // global_load_lds B(kt)
#pragma unroll
    for (int i = 0; i < 4; ++i) {
      const int r = w * 32 + i * 8 + (lane >> 3);
      const int u = (lane & 7) ^ (r & 7);
      GLD16(W1kt + (((size_t)(col0 + r)) << 10) + kt * 64 + u * 8, ldsB_dst + i * 1024);
    }
    __syncthreads();  // (b) staging visible
    // issue-early: A loads for kt+1 fly under this tile's MFMA
    if (kt < 15) {
#pragma unroll
      for (int j = 0; j < 8; ++j)
        Ar[j] = *(const f32x4*)(gA + (kt + 1) * 64 + (size_t)j * 16 * 1024);
    }
    // compute
#pragma unroll
    for (int kk = 0; kk < 2; ++kk) {
      bf16x8 af[4], bf[4];
#pragma unroll
      for (int mf = 0; mf < 4; ++mf) {
        const int ra = wm * 64 + mf * 16 + c16;
        af[mf] = *(const bf16x8*)(Alds + ra * 128 + (((kk * 4 + q4) ^ (ra & 7)) << 4));
      }
#pragma unroll
      for (int nf = 0; nf < 4; ++nf) {
        const int ca = wn * 64 + nf * 16 + c16;
        bf[nf] = *(const bf16x8*)(Blds + ca * 128 + (((kk * 4 + q4) ^ (ca & 7)) << 4));
      }
#pragma unroll
      for (int nf = 0; nf < 4; ++nf)
#pragma unroll
        for (int mf = 0; mf < 4; ++mf) acc[mf][nf] = MFMA16(af[mf], bf[nf], acc[mf][nf]);
    }
  }

  // ---- epilogue: v = acc + qterm + cov*W1c; p_part = sum_cols tanh(v)*W2 ----
  float covv[4][4];
#pragma unroll
  for (int mf = 0; mf < 4; ++mf)
#pragma unroll
    for (int r = 0; r < 4; ++r)
      covv[mf][r] = coverage[row0 + wm * 64 + mf * 16 + q4 * 4 + r];

  float p_part[4][4];
#pragma unroll
  for (int mf = 0; mf < 4; ++mf)
#pragma unroll
    for (int r = 0; r < 4; ++r) p_part[mf][r] = 0.f;

#pragma unroll
  for (int nf = 0; nf < 4; ++nf) {
    const int col = col0 + wn * 64 + nf * 16 + c16;
    const float qt = qterm[b * 1024 + col];
    const float w1c = W1[(size_t)2048 * 1024 + col];
    const float w2 = W2[col];
#pragma unroll
    for (int mf = 0; mf < 4; ++mf)
#pragma unroll
      for (int r = 0; r < 4; ++r) {
        float v = acc[mf][nf][r] + qt + covv[mf][r] * w1c;
        p_part[mf][r] += fast_tanh(v) * w2;
      }
  }

  // reduce over 16 col-lanes, then across the wn pair via Sred
#pragma unroll
  for (int mf = 0; mf < 4; ++mf)
#pragma unroll
    for (int r = 0; r < 4; ++r) {
      float p = p_part[mf][r];
      p += __shfl_xor(p, 1);
      p += __shfl_xor(p, 2);
      p += __shfl_xor(p, 4);
      p += __shfl_xor(p, 8);
      if (c16 == 0) Sred[w * 64 + mf * 16 + q4 * 4 + r] = p;
    }
  __syncthreads();
  if (tid < 128) {
    const int wmv = tid >> 6, j = tid & 63;
    float s = Sred[wmv * 128 + j] + Sred[wmv * 128 + 64 + j];
    scores_part[(size_t)colgrp * 32768 + row0 + tid] = s;
  }
}

// ---------------- softmax over L per batch (sums 8 colgrp partials) ----------------
__global__ void softmax_kernel(const float* __restrict__ sp, float* __restrict__ att) {
  const int b = blockIdx.x;
  const int tid = threadIdx.x;
  float* a = att + b * 2048;
  __shared__ float red[4];
  float mx = -1e30f;
  for (int l = tid; l < 2048; l += 256) {
    float v = 0.f;
#pragma unroll
    for (int g = 0; g < 8; ++g) v += sp[(size_t)g * 32768 + b * 2048 + l];
    a[l] = v;
    mx = fmaxf(mx, v);
  }
#pragma unroll
  for (int o = 1; o < 64; o <<= 1) mx = fmaxf(mx, __shfl_xor(mx, o));
  if ((tid & 63) == 0) red[tid >> 6] = mx;
  __syncthreads();
  mx = fmaxf(fmaxf(red[0], red[1]), fmaxf(red[2], red[3]));
  __syncthreads();
  float sum = 0.f;
  for (int l = tid; l < 2048; l += 256) {
    float e = __expf(a[l] - mx);
    a[l] = e;
    sum += e;
  }
#pragma unroll
  for (int o = 1; o < 64; o <<= 1) sum += __shfl_xor(sum, o);
  if ((tid & 63) == 0) red[tid >> 6] = sum;
  __syncthreads();
  sum = red[0] + red[1] + red[2] + red[3];
  const float inv = 1.0f / sum;
  for (int l = tid; l < 2048; l += 256) a[l] *= inv;
}

// ---------------- ctx_part[sl][b][j] = sum over 128 rows of att*keys (no atomics) ----------------
__global__ void ctxpre_kernel(const float* __restrict__ keys, const float* __restrict__ att,
                              float* __restrict__ ctx_part) {
  const int b = blockIdx.x;   // 16
  const int sl = blockIdx.y;  // 16 slices of 128 rows
  const int tid = threadIdx.x;  // 256: unit u = tid&255 covers cols u*4..u*4+3
  const float* ab = att + b * 2048 + sl * 128;
  const f32x4* kp = (const f32x4*)(keys + ((size_t)b * 2048 + sl * 128) * 1024) + tid;
  f32x4 acc = {0.f, 0.f, 0.f, 0.f};
#pragma unroll 4
  for (int l = 0; l < 128; ++l) acc += kp[(size_t)l * 256] * ab[l];
  *(f32x4*)(ctx_part + ((size_t)(sl * 16 + b)) * 1024 + tid * 4) = acc;
}

// ---------------- ctx_pre[b][j] = sum_sl ctx_part[sl][b][j] ----------------
__global__ void ctxreduce_kernel(const float* __restrict__ ctx_part, float* __restrict__ ctx_pre) {
  const int i = blockIdx.x * 256 + threadIdx.x;  // 0..16383 = b*1024+j
  const int b = i >> 10, j = i & 1023;
  float s = 0.f;
#pragma unroll
  for (int sl = 0; sl < 16; ++sl) s += ctx_part[((size_t)(sl * 16 + b)) * 1024 + j];
  ctx_pre[i] = s;
}

// ---------------- context[b][h] = sum_j ctx_pre[b][j] * Wr[j][h] ----------------
__global__ void context_kernel(const float* __restrict__ ctx_pre, const float* __restrict__ Wr,
                               float* __restrict__ out) {
  const int b = blockIdx.y;
  const int h = blockIdx.x * 256 + threadIdx.x;
  const float* cp = ctx_pre + b * 1024;
  float acc = 0.f;
#pragma unroll 8
  for (int j = 0; j < 1024; ++j) acc += cp[j] * Wr[(size_t)j * 512 + h];
  out[b * 512 + h] = acc;
}

extern "C" void kernel_launch(void* const* d_in, const int* in_sizes, int n_in, void* d_out,
                              int out_size, void* d_ws, size_t ws_size, hipStream_t stream) {
  const float* query = (const float*)d_in[0];     // (16,1,1024)
  const float* keys = (const float*)d_in[1];      // (16,2048,1024)
  const float* coverage = (const float*)d_in[2];  // (16,2048,1)
  const float* W1 = (const float*)d_in[3];        // (2049,1024)
  const float* b1 = (const float*)d_in[4];        // (1024,)
  const float* W2 = (const float*)d_in[5];        // (1024,1)
  const float* Wr = (const float*)d_in[6];        // (1024,512)
  float* out = (float*)d_out;
  char* ws = (char*)d_ws;

  float* scores_part = (float*)ws;            // 8*32768 f32 = 1MB @ 0
  float* ctx_part = (float*)ws;               // 16*16*1024 f32 = 1MB, ALIASES scores_part
                                              // (scores_part dead after softmax; same stream order)
  float* ctx_pre = (float*)(ws + 1048576);    // 16384 f32
  float* qterm = (float*)(ws + 1114112);      // 16384 f32
  unsigned short* W1kt = (unsigned short*)(ws + 1179648);  // 1M bf16 (2MB)

  float* context_out = out;     // 16*512
  float* att_out = out + 8192;  // 16*2048

  transpose_w1k<<<dim3(16, 16), dim3(256), 0, stream>>>(W1, W1kt);
  qterm_kernel<<<dim3(4, 16), dim3(256), 0, stream>>>(query, W1, b1, qterm);
  gemm_score_kernel<<<dim3(2048), dim3(256), 0, stream>>>(keys, W1kt, qterm, coverage, W1, W2,
                                                          scores_part);
  softmax_kernel<<<dim3(16), dim3(256), 0, stream>>>(scores_part, att_out);
  ctxpre_kernel<<<dim3(16, 16), dim3(256), 0, stream>>>(keys, att_out, ctx_part);
  ctxreduce_kernel<<<dim3(64), dim3(256), 0, stream>>>(ctx_part, ctx_pre);
  context_kernel<<<dim3(2, 16), dim3(256), 0, stream>>>(ctx_pre, Wr, context_out);
}

// Round 7
// 171.477 us; speedup vs baseline: 1.9141x; 1.3330x over previous
//
#include <hip/hip_runtime.h>
#include <hip/hip_bf16.h>
#include <stdint.h>

typedef short bf16x8 __attribute__((ext_vector_type(8)));
typedef float f32x4 __attribute__((ext_vector_type(4)));
typedef unsigned int u32x2 __attribute__((ext_vector_type(2)));

__device__ __forceinline__ uint32_t pack2f(float lo, float hi) {
  union { __hip_bfloat162 h; uint32_t u; } c;
  c.h.x = __float2bfloat16(lo);
  c.h.y = __float2bfloat16(hi);
  return c.u;
}

__device__ __forceinline__ unsigned short f32_to_bf16(float f) {
  union { __hip_bfloat16 h; unsigned short u; } c;
  c.h = __float2bfloat16(f);
  return c.u;
}

__device__ __forceinline__ float fast_tanh(float x) {
  float e = __builtin_amdgcn_exp2f(x * 2.8853900817779268f);
  return 1.0f - 2.0f * __builtin_amdgcn_rcpf(e + 1.0f);
}

#define GLD16(g, l)                                                                    \
  __builtin_amdgcn_global_load_lds((const __attribute__((address_space(1))) void*)(g), \
                                   (__attribute__((address_space(3))) void*)(l), 16, 0, 0)

// ---------------- W1k transpose + bf16 convert: W1kt[j][k] = bf16(W1[1024+k][j]) ----------------
__global__ void transpose_w1k(const float* __restrict__ W1, unsigned short* __restrict__ W1kt) {
  __shared__ float t[64][65];
  const int kb = blockIdx.x * 64;
  const int jb = blockIdx.y * 64;
  const int c = threadIdx.x & 63;
  const int r = threadIdx.x >> 6;  // 0..3
#pragma unroll
  for (int i = 0; i < 16; ++i) {
    const int k = i * 4 + r;
    t[k][c] = W1[(size_t)(1024 + kb + k) * 1024 + (jb + c)];
  }
  __syncthreads();
#pragma unroll
  for (int i = 0; i < 16; ++i) {
    const int j = i * 4 + r;
    W1kt[(size_t)(jb + j) * 1024 + (kb + c)] = f32_to_bf16(t[c][j]);
  }
}

// ---------------- qterm[b][j] = b1[j] + sum_k query[b][k]*W1[k][j] ----------------
__global__ void qterm_kernel(const float* __restrict__ query, const float* __restrict__ W1,
                             const float* __restrict__ b1, float* __restrict__ qterm) {
  const int b = blockIdx.y;
  const int j = blockIdx.x * 64 + (threadIdx.x & 63);
  const int kq = threadIdx.x >> 6;  // 0..3
  __shared__ float part[4][64];
  const float* q = query + b * 1024 + kq * 256;
  const float* wp = W1 + (size_t)(kq * 256) * 1024 + j;
  float acc = 0.f;
#pragma unroll 8
  for (int k = 0; k < 256; ++k) acc += q[k] * wp[(size_t)k * 1024];
  part[kq][threadIdx.x & 63] = acc;
  __syncthreads();
  if (threadIdx.x < 64) {
    const int jj = blockIdx.x * 64 + threadIdx.x;
    qterm[b * 1024 + jj] = b1[jj] + part[0][threadIdx.x] + part[1][threadIdx.x] +
                           part[2][threadIdx.x] + part[3][threadIdx.x];
  }
}

// ---------------- fused GEMM + tanh + W2-reduce (counted-vmcnt pipeline) ----------------
// 256 thr / 4 waves (2x2 of 64x64), tile 128x128, BK=64, 16 k-tiles, grid 2048.
// Double-buffered A and B. B: global_load_lds with swizzle folded into global src.
// A: fp32 reg-staged -> bf16 pack -> swizzled ds_write_b64.
// Pipeline: issue GLD B(t+1) + write A(t+1) + issue A-loads(t+2); compute t;
// s_waitcnt vmcnt(8) (drains exactly B(t+1); A(t+2) stays in flight) + raw barrier.
#define MFMA16(a, b, c) __builtin_amdgcn_mfma_f32_16x16x32_bf16(a, b, c, 0, 0, 0)
#define SBAR0() __builtin_amdgcn_sched_barrier(0)

#define STAGE_B(t, Bdst)                                          \
  _Pragma("unroll") for (int i = 0; i < 4; ++i) {                 \
    const int r = w * 32 + i * 8 + (lane >> 3);                   \
    const int u = (lane & 7) ^ (r & 7);                           \
    GLD16(W1kt + (((size_t)(col0 + r)) << 10) + (t) * 64 + u * 8, \
          (Bdst) + w * 4096 + lane * 16 + i * 1024);              \
  }

#define LOAD_A(t)                                 \
  _Pragma("unroll") for (int j = 0; j < 8; ++j)   \
      Ar[j] = *(const f32x4*)(gA + (t) * 64 + (size_t)j * 16 * 1024);

#define WRITE_A(Adst)                                                 \
  _Pragma("unroll") for (int j = 0; j < 8; ++j) {                     \
    const int r = arow + j * 16;                                      \
    u32x2 p;                                                          \
    p.x = pack2f(Ar[j].x, Ar[j].y);                                   \
    p.y = pack2f(Ar[j].z, Ar[j].w);                                   \
    *(u32x2*)((Adst) + r * 128 + (((aun ^ (r & 7)) << 4) + auh)) = p; \
  }

#define COMPUTE(Asrc, Bsrc)                                                                   \
  _Pragma("unroll") for (int kk = 0; kk < 2; ++kk) {                                          \
    bf16x8 af[4], bfv[4];                                                                     \
    _Pragma("unroll") for (int mf = 0; mf < 4; ++mf) {                                        \
      const int ra = wm * 64 + mf * 16 + c16;                                                 \
      af[mf] = *(const bf16x8*)((Asrc) + ra * 128 + (((kk * 4 + q4) ^ (ra & 7)) << 4));       \
    }                                                                                         \
    _Pragma("unroll") for (int nf = 0; nf < 4; ++nf) {                                        \
      const int ca = wn * 64 + nf * 16 + c16;                                                 \
      bfv[nf] = *(const bf16x8*)((Bsrc) + ca * 128 + (((kk * 4 + q4) ^ (ca & 7)) << 4));      \
    }                                                                                         \
    _Pragma("unroll") for (int nf = 0; nf < 4; ++nf)                                          \
        _Pragma("unroll") for (int mf = 0; mf < 4; ++mf) acc[mf][nf] =                        \
            MFMA16(af[mf], bfv[nf], acc[mf][nf]);                                             \
  }

#define DRAIN_BARRIER(t)                                                  \
  if ((t) < 14) asm volatile("s_waitcnt vmcnt(8) lgkmcnt(0)" ::: "memory"); \
  else          asm volatile("s_waitcnt vmcnt(0) lgkmcnt(0)" ::: "memory"); \
  __builtin_amdgcn_s_barrier();                                           \
  SBAR0();

#define PIPE_ITER(t, Ac, Bc, An, Bn)   \
  if ((t) < 15) {                      \
    STAGE_B((t) + 1, Bn);              \
    SBAR0();                           \
    WRITE_A(An);                       \
    if ((t) < 14) LOAD_A((t) + 2);     \
    SBAR0();                           \
  }                                    \
  COMPUTE(Ac, Bc);                     \
  SBAR0();                             \
  DRAIN_BARRIER(t)

__global__ __launch_bounds__(256, 2) void gemm_score_kernel(
    const float* __restrict__ keys, const unsigned short* __restrict__ W1kt,
    const float* __restrict__ qterm, const float* __restrict__ coverage,
    const float* __restrict__ W1, const float* __restrict__ W2,
    float* __restrict__ scores_part) {
  __shared__ __align__(16) unsigned char lds[66560];
  unsigned char* A0 = lds;
  unsigned char* A1 = lds + 16384;
  unsigned char* B0 = lds + 32768;
  unsigned char* B1 = lds + 49152;
  float* Sred = (float*)(lds + 65536);  // 4 x 64 f32

  const int tid = threadIdx.x;
  const int bid = blockIdx.x;
  // bijective XCD clustering: XCD x handles rowgrps [32x,32x+32), all 8 colgrps
  const int xcd = bid & 7;
  const int idx = bid >> 3;                  // 0..255
  const int rowgrp = xcd * 32 + (idx >> 3);  // 0..255
  const int colgrp = idx & 7;                // 0..7
  const int row0 = rowgrp * 128;
  const int col0 = colgrp * 128;
  const int b = row0 >> 11;
  const int w = tid >> 6;
  const int wm = w >> 1, wn = w & 1;
  const int lane = tid & 63;
  const int c16 = lane & 15, q4 = lane >> 4;

  // A staging map: thread t covers rows (t>>4)+j*16 (j=0..7), k-floats (t&15)*4
  const int arow = tid >> 4;
  const int akf = (tid & 15) * 4;
  const float* gA = keys + (size_t)(row0 + arow) * 1024 + akf;
  const int auh = (tid & 1) * 8;
  const int aun = (tid & 15) >> 1;

  f32x4 acc[4][4];  // [mf][nf]
  const f32x4 zz = {0.f, 0.f, 0.f, 0.f};
#pragma unroll
  for (int mf = 0; mf < 4; ++mf)
#pragma unroll
    for (int nf = 0; nf < 4; ++nf) acc[mf][nf] = zz;

  f32x4 Ar[8];

  // ---- prologue: A(0) regs first (oldest), then B(0) GLD; write A(0); issue A(1) ----
  LOAD_A(0);
  SBAR0();
  STAGE_B(0, B0);
  SBAR0();
  WRITE_A(A0);  // compiler inserts vmcnt(4): drains A(0), leaves B(0) in flight
  LOAD_A(1);
  SBAR0();
  asm volatile("s_waitcnt vmcnt(8) lgkmcnt(0)" ::: "memory");  // drains B(0); A(1) flies
  __builtin_amdgcn_s_barrier();
  SBAR0();

#pragma unroll 1
  for (int th = 0; th < 8; ++th) {
    const int t0 = th * 2, t1 = th * 2 + 1;
    PIPE_ITER(t0, A0, B0, A1, B1);
    PIPE_ITER(t1, A1, B1, A0, B0);
  }

  // ---- epilogue: v = acc + qterm + cov*W1c; p_part = sum_cols tanh(v)*W2 ----
  float covv[4][4];
#pragma unroll
  for (int mf = 0; mf < 4; ++mf)
#pragma unroll
    for (int r = 0; r < 4; ++r)
      covv[mf][r] = coverage[row0 + wm * 64 + mf * 16 + q4 * 4 + r];

  float p_part[4][4];
#pragma unroll
  for (int mf = 0; mf < 4; ++mf)
#pragma unroll
    for (int r = 0; r < 4; ++r) p_part[mf][r] = 0.f;

#pragma unroll
  for (int nf = 0; nf < 4; ++nf) {
    const int col = col0 + wn * 64 + nf * 16 + c16;
    const float qt = qterm[b * 1024 + col];
    const float w1c = W1[(size_t)2048 * 1024 + col];
    const float w2 = W2[col];
#pragma unroll
    for (int mf = 0; mf < 4; ++mf)
#pragma unroll
      for (int r = 0; r < 4; ++r) {
        float v = acc[mf][nf][r] + qt + covv[mf][r] * w1c;
        p_part[mf][r] += fast_tanh(v) * w2;
      }
  }

  // reduce over 16 col-lanes, then across waves via Sred
#pragma unroll
  for (int mf = 0; mf < 4; ++mf)
#pragma unroll
    for (int r = 0; r < 4; ++r) {
      float p = p_part[mf][r];
      p += __shfl_xor(p, 1);
      p += __shfl_xor(p, 2);
      p += __shfl_xor(p, 4);
      p += __shfl_xor(p, 8);
      if (c16 == 0) Sred[w * 64 + mf * 16 + q4 * 4 + r] = p;
    }
  __syncthreads();
  if (tid < 128) {
    const int wmv = tid >> 6, j = tid & 63;
    float s = Sred[wmv * 128 + j] + Sred[wmv * 128 + 64 + j];
    scores_part[(size_t)colgrp * 32768 + row0 + tid] = s;
  }
}

// ---------------- softmax over L per batch (sums 8 colgrp partials) ----------------
__global__ void softmax_kernel(const float* __restrict__ sp, float* __restrict__ att) {
  const int b = blockIdx.x;
  const int tid = threadIdx.x;
  float* a = att + b * 2048;
  __shared__ float red[4];
  float mx = -1e30f;
  for (int l = tid; l < 2048; l += 256) {
    float v = 0.f;
#pragma unroll
    for (int g = 0; g < 8; ++g) v += sp[(size_t)g * 32768 + b * 2048 + l];
    a[l] = v;
    mx = fmaxf(mx, v);
  }
#pragma unroll
  for (int o = 1; o < 64; o <<= 1) mx = fmaxf(mx, __shfl_xor(mx, o));
  if ((tid & 63) == 0) red[tid >> 6] = mx;
  __syncthreads();
  mx = fmaxf(fmaxf(red[0], red[1]), fmaxf(red[2], red[3]));
  __syncthreads();
  float sum = 0.f;
  for (int l = tid; l < 2048; l += 256) {
    float e = __expf(a[l] - mx);
    a[l] = e;
    sum += e;
  }
#pragma unroll
  for (int o = 1; o < 64; o <<= 1) sum += __shfl_xor(sum, o);
  if ((tid & 63) == 0) red[tid >> 6] = sum;
  __syncthreads();
  sum = red[0] + red[1] + red[2] + red[3];
  const float inv = 1.0f / sum;
  for (int l = tid; l < 2048; l += 256) a[l] *= inv;
}

// ---------------- ctx_part[sl][b][j] = sum over 128 rows of att*keys (no atomics) ----------------
__global__ void ctxpre_kernel(const float* __restrict__ keys, const float* __restrict__ att,
                              float* __restrict__ ctx_part) {
  const int b = blockIdx.x;     // 16
  const int sl = blockIdx.y;    // 16 slices of 128 rows
  const int tid = threadIdx.x;  // 256
  const float* ab = att + b * 2048 + sl * 128;
  const f32x4* kp = (const f32x4*)(keys + ((size_t)b * 2048 + sl * 128) * 1024) + tid;
  f32x4 acc = {0.f, 0.f, 0.f, 0.f};
#pragma unroll 4
  for (int l = 0; l < 128; ++l) acc += kp[(size_t)l * 256] * ab[l];
  *(f32x4*)(ctx_part + ((size_t)(sl * 16 + b)) * 1024 + tid * 4) = acc;
}

// ---------------- ctx_pre[b][j] = sum_sl ctx_part[sl][b][j] ----------------
__global__ void ctxreduce_kernel(const float* __restrict__ ctx_part, float* __restrict__ ctx_pre) {
  const int i = blockIdx.x * 256 + threadIdx.x;  // 0..16383 = b*1024+j
  const int b = i >> 10, j = i & 1023;
  float s = 0.f;
#pragma unroll
  for (int sl = 0; sl < 16; ++sl) s += ctx_part[((size_t)(sl * 16 + b)) * 1024 + j];
  ctx_pre[i] = s;
}

// ---------------- context[b][h] = sum_j ctx_pre[b][j] * Wr[j][h] ----------------
__global__ void context_kernel(const float* __restrict__ ctx_pre, const float* __restrict__ Wr,
                               float* __restrict__ out) {
  const int b = blockIdx.y;
  const int h = blockIdx.x * 64 + (threadIdx.x & 63);
  const int jq = threadIdx.x >> 6;  // 0..3
  __shared__ float part[4][64];
  const float* cp = ctx_pre + b * 1024 + jq * 256;
  const float* wp = Wr + (size_t)(jq * 256) * 512 + h;
  float acc = 0.f;
#pragma unroll 8
  for (int k = 0; k < 256; ++k) acc += cp[k] * wp[(size_t)k * 512];
  part[jq][threadIdx.x & 63] = acc;
  __syncthreads();
  if (threadIdx.x < 64)
    out[b * 512 + blockIdx.x * 64 + threadIdx.x] = part[0][threadIdx.x] + part[1][threadIdx.x] +
                                                   part[2][threadIdx.x] + part[3][threadIdx.x];
}

extern "C" void kernel_launch(void* const* d_in, const int* in_sizes, int n_in, void* d_out,
                              int out_size, void* d_ws, size_t ws_size, hipStream_t stream) {
  const float* query = (const float*)d_in[0];     // (16,1,1024)
  const float* keys = (const float*)d_in[1];      // (16,2048,1024)
  const float* coverage = (const float*)d_in[2];  // (16,2048,1)
  const float* W1 = (const float*)d_in[3];        // (2049,1024)
  const float* b1 = (const float*)d_in[4];        // (1024,)
  const float* W2 = (const float*)d_in[5];        // (1024,1)
  const float* Wr = (const float*)d_in[6];        // (1024,512)
  float* out = (float*)d_out;
  char* ws = (char*)d_ws;

  float* scores_part = (float*)ws;          // 8*32768 f32 = 1MB @ 0
  float* ctx_part = (float*)ws;             // 16*16*1024 f32 = 1MB, ALIASES scores_part
                                            // (scores_part dead after softmax; serial stream)
  float* ctx_pre = (float*)(ws + 1048576);  // 16384 f32
  float* qterm = (float*)(ws + 1114112);    // 16384 f32
  unsigned short* W1kt = (unsigned short*)(ws + 1179648);  // 1M bf16 (2MB)

  float* context_out = out;     // 16*512
  float* att_out = out + 8192;  // 16*2048

  transpose_w1k<<<dim3(16, 16), dim3(256), 0, stream>>>(W1, W1kt);
  qterm_kernel<<<dim3(16, 16), dim3(256), 0, stream>>>(query, W1, b1, qterm);
  gemm_score_kernel<<<dim3(2048), dim3(256), 0, stream>>>(keys, W1kt, qterm, coverage, W1, W2,
                                                          scores_part);
  softmax_kernel<<<dim3(16), dim3(256), 0, stream>>>(scores_part, att_out);
  ctxpre_kernel<<<dim3(16, 16), dim3(256), 0, stream>>>(keys, att_out, ctx_part);
  ctxreduce_kernel<<<dim3(64), dim3(256), 0, stream>>>(ctx_part, ctx_pre);
  context_kernel<<<dim3(8, 16), dim3(256), 0, stream>>>(ctx_pre, Wr, context_out);
}

// Round 8
// 160.511 us; speedup vs baseline: 2.0449x; 1.0683x over previous
//
#include <hip/hip_runtime.h>
#include <hip/hip_bf16.h>
#include <stdint.h>

typedef short bf16x8 __attribute__((ext_vector_type(8)));
typedef float f32x4 __attribute__((ext_vector_type(4)));
typedef unsigned int u32x2 __attribute__((ext_vector_type(2)));

__device__ __forceinline__ uint32_t pack2f(float lo, float hi) {
  union { __hip_bfloat162 h; uint32_t u; } c;
  c.h.x = __float2bfloat16(lo);
  c.h.y = __float2bfloat16(hi);
  return c.u;
}

__device__ __forceinline__ unsigned short f32_to_bf16(float f) {
  union { __hip_bfloat16 h; unsigned short u; } c;
  c.h = __float2bfloat16(f);
  return c.u;
}

__device__ __forceinline__ float fast_tanh(float x) {
  float e = __builtin_amdgcn_exp2f(x * 2.8853900817779268f);
  return 1.0f - 2.0f * __builtin_amdgcn_rcpf(e + 1.0f);
}

#define GLD16(g, l)                                                                    \
  __builtin_amdgcn_global_load_lds((const __attribute__((address_space(1))) void*)(g), \
                                   (__attribute__((address_space(3))) void*)(l), 16, 0, 0)

// ---------------- W1k transpose + bf16 convert: W1kt[j][k] = bf16(W1[1024+k][j]) ----------------
__global__ void transpose_w1k(const float* __restrict__ W1, unsigned short* __restrict__ W1kt) {
  __shared__ float t[64][65];
  const int kb = blockIdx.x * 64;
  const int jb = blockIdx.y * 64;
  const int c = threadIdx.x & 63;
  const int r = threadIdx.x >> 6;  // 0..3
#pragma unroll
  for (int i = 0; i < 16; ++i) {
    const int k = i * 4 + r;
    t[k][c] = W1[(size_t)(1024 + kb + k) * 1024 + (jb + c)];
  }
  __syncthreads();
#pragma unroll
  for (int i = 0; i < 16; ++i) {
    const int j = i * 4 + r;
    W1kt[(size_t)(jb + j) * 1024 + (kb + c)] = f32_to_bf16(t[c][j]);
  }
}

// ---------------- qterm[b][j] = b1[j] + sum_k query[b][k]*W1[k][j] ----------------
__global__ void qterm_kernel(const float* __restrict__ query, const float* __restrict__ W1,
                             const float* __restrict__ b1, float* __restrict__ qterm) {
  const int b = blockIdx.y;
  const int j = blockIdx.x * 64 + (threadIdx.x & 63);
  const int kq = threadIdx.x >> 6;  // 0..3
  __shared__ float part[4][64];
  const float* q = query + b * 1024 + kq * 256;
  const float* wp = W1 + (size_t)(kq * 256) * 1024 + j;
  float acc = 0.f;
#pragma unroll 8
  for (int k = 0; k < 256; ++k) acc += q[k] * wp[(size_t)k * 1024];
  part[kq][threadIdx.x & 63] = acc;
  __syncthreads();
  if (threadIdx.x < 64) {
    const int jj = blockIdx.x * 64 + threadIdx.x;
    qterm[b * 1024 + jj] = b1[jj] + part[0][threadIdx.x] + part[1][threadIdx.x] +
                           part[2][threadIdx.x] + part[3][threadIdx.x];
  }
}

// ---------------- fused GEMM + tanh + W2-reduce ----------------
// 256 thr / 4 waves (2x2 of 64x64), tile 128x128, BK=64, 16 k-tiles, grid 2048.
// A single LDS buffer (written between barriers), B double-buffered via GLD.
// Schedule per kt: STAGE_B(t+1) / COMPUTE(t) / drain(all >=1 phase old)+bar /
// WRITE_A(t+1)+LOAD_A(t+2) / lgkm-only bar (A(t+2) stays in flight).
#define MFMA16(a, b, c) __builtin_amdgcn_mfma_f32_16x16x32_bf16(a, b, c, 0, 0, 0)
#define SBAR0() __builtin_amdgcn_sched_barrier(0)

#define STAGE_B(t, Bdst)                                          \
  _Pragma("unroll") for (int i = 0; i < 4; ++i) {                 \
    const int r = w * 32 + i * 8 + (lane >> 3);                   \
    const int u = (lane & 7) ^ (r & 7);                           \
    GLD16(W1kt + (((size_t)(col0 + r)) << 10) + (t) * 64 + u * 8, \
          (Bdst) + w * 4096 + lane * 16 + i * 1024);              \
  }

#define LOAD_A(t)                               \
  _Pragma("unroll") for (int j = 0; j < 8; ++j) \
      Ar[j] = *(const f32x4*)(gA + (t) * 64 + (size_t)j * 16 * 1024);

#define WRITE_A()                                                     \
  _Pragma("unroll") for (int j = 0; j < 8; ++j) {                     \
    const int r = arow + j * 16;                                      \
    u32x2 p;                                                          \
    p.x = pack2f(Ar[j].x, Ar[j].y);                                   \
    p.y = pack2f(Ar[j].z, Ar[j].w);                                   \
    *(u32x2*)(Alds + r * 128 + (((aun ^ (r & 7)) << 4) + auh)) = p;   \
  }

#define COMPUTE(Bsrc)                                                                        \
  _Pragma("unroll") for (int kk = 0; kk < 2; ++kk) {                                         \
    bf16x8 af[4], bfv[4];                                                                    \
    _Pragma("unroll") for (int mf = 0; mf < 4; ++mf) {                                       \
      const int ra = wm * 64 + mf * 16 + c16;                                                \
      af[mf] = *(const bf16x8*)(Alds + ra * 128 + (((kk * 4 + q4) ^ (ra & 7)) << 4));        \
    }                                                                                        \
    _Pragma("unroll") for (int nf = 0; nf < 4; ++nf) {                                       \
      const int ca = wn * 64 + nf * 16 + c16;                                                \
      bfv[nf] = *(const bf16x8*)((Bsrc) + ca * 128 + (((kk * 4 + q4) ^ (ca & 7)) << 4));     \
    }                                                                                        \
    _Pragma("unroll") for (int nf = 0; nf < 4; ++nf)                                         \
        _Pragma("unroll") for (int mf = 0; mf < 4; ++mf) acc[mf][nf] =                       \
            MFMA16(af[mf], bfv[nf], acc[mf][nf]);                                            \
  }

// drain: everything outstanding is >= 1 compute phase old -> cheap
#define DRAIN_BAR()                                                   \
  asm volatile("s_waitcnt vmcnt(0) lgkmcnt(0)" ::: "memory");         \
  __builtin_amdgcn_s_barrier();

// A-write visibility only; A(t+2) global loads stay in flight
#define LGKM_BAR()                                                    \
  asm volatile("s_waitcnt lgkmcnt(0)" ::: "memory");                  \
  __builtin_amdgcn_s_barrier();

#define PIPE_ITER(t, Bc, Bn)          \
  if ((t) < 15) { STAGE_B((t) + 1, Bn); } \
  SBAR0();                            \
  COMPUTE(Bc);                        \
  if ((t) < 15) {                     \
    DRAIN_BAR();                      \
    WRITE_A();                        \
    if ((t) < 14) LOAD_A((t) + 2);    \
    LGKM_BAR();                       \
  }

__global__ __launch_bounds__(256, 3) void gemm_score_kernel(
    const float* __restrict__ keys, const unsigned short* __restrict__ W1kt,
    const float* __restrict__ qterm, const float* __restrict__ coverage,
    const float* __restrict__ W1, const float* __restrict__ W2,
    float* __restrict__ scores_part) {
  __shared__ __align__(16) unsigned char lds[50176];
  unsigned char* Alds = lds;            // 16KB
  unsigned char* B0 = lds + 16384;      // 16KB
  unsigned char* B1 = lds + 32768;      // 16KB
  float* Sred = (float*)(lds + 49152);  // 4 x 64 f32

  const int tid = threadIdx.x;
  const int bid = blockIdx.x;
  // bijective XCD clustering: XCD x handles rowgrps [32x,32x+32), all 8 colgrps
  const int xcd = bid & 7;
  const int idx = bid >> 3;                  // 0..255
  const int rowgrp = xcd * 32 + (idx >> 3);  // 0..255
  const int colgrp = idx & 7;                // 0..7
  const int row0 = rowgrp * 128;
  const int col0 = colgrp * 128;
  const int b = row0 >> 11;
  const int w = tid >> 6;
  const int wm = w >> 1, wn = w & 1;
  const int lane = tid & 63;
  const int c16 = lane & 15, q4 = lane >> 4;

  // A staging map: thread t covers rows (t>>4)+j*16 (j=0..7), k-floats (t&15)*4
  const int arow = tid >> 4;
  const int akf = (tid & 15) * 4;
  const float* gA = keys + (size_t)(row0 + arow) * 1024 + akf;
  const int auh = (tid & 1) * 8;
  const int aun = (tid & 15) >> 1;

  f32x4 acc[4][4];  // [mf][nf]
  const f32x4 zz = {0.f, 0.f, 0.f, 0.f};
#pragma unroll
  for (int mf = 0; mf < 4; ++mf)
#pragma unroll
    for (int nf = 0; nf < 4; ++nf) acc[mf][nf] = zz;

  f32x4 Ar[8];

  // ---- prologue ----
  LOAD_A(0);
  SBAR0();
  STAGE_B(0, B0);  // B(0) younger than A(0), older than A(1)
  SBAR0();
  WRITE_A();       // compiler waits A(0) loads precisely (B(0) stays in flight)
  LOAD_A(1);
  SBAR0();
  asm volatile("s_waitcnt vmcnt(8) lgkmcnt(0)" ::: "memory");  // drains B(0); A(1) flies
  __builtin_amdgcn_s_barrier();

#pragma unroll 1
  for (int th = 0; th < 8; ++th) {
    const int t0 = th * 2, t1 = th * 2 + 1;
    PIPE_ITER(t0, B0, B1);
    PIPE_ITER(t1, B1, B0);
  }

  // ---- epilogue: v = acc + qterm + cov*W1c; p_part = sum_cols tanh(v)*W2 ----
  float covv[4][4];
#pragma unroll
  for (int mf = 0; mf < 4; ++mf)
#pragma unroll
    for (int r = 0; r < 4; ++r)
      covv[mf][r] = coverage[row0 + wm * 64 + mf * 16 + q4 * 4 + r];

  float p_part[4][4];
#pragma unroll
  for (int mf = 0; mf < 4; ++mf)
#pragma unroll
    for (int r = 0; r < 4; ++r) p_part[mf][r] = 0.f;

#pragma unroll
  for (int nf = 0; nf < 4; ++nf) {
    const int col = col0 + wn * 64 + nf * 16 + c16;
    const float qt = qterm[b * 1024 + col];
    const float w1c = W1[(size_t)2048 * 1024 + col];
    const float w2 = W2[col];
#pragma unroll
    for (int mf = 0; mf < 4; ++mf)
#pragma unroll
      for (int r = 0; r < 4; ++r) {
        float v = acc[mf][nf][r] + qt + covv[mf][r] * w1c;
        p_part[mf][r] += fast_tanh(v) * w2;
      }
  }

  // reduce over 16 col-lanes, then across waves via Sred
#pragma unroll
  for (int mf = 0; mf < 4; ++mf)
#pragma unroll
    for (int r = 0; r < 4; ++r) {
      float p = p_part[mf][r];
      p += __shfl_xor(p, 1);
      p += __shfl_xor(p, 2);
      p += __shfl_xor(p, 4);
      p += __shfl_xor(p, 8);
      if (c16 == 0) Sred[w * 64 + mf * 16 + q4 * 4 + r] = p;
    }
  __syncthreads();
  if (tid < 128) {
    const int wmv = tid >> 6, j = tid & 63;
    float s = Sred[wmv * 128 + j] + Sred[wmv * 128 + 64 + j];
    scores_part[(size_t)colgrp * 32768 + row0 + tid] = s;
  }
}

// ---------------- softmax over L per batch (sums 8 colgrp partials) ----------------
__global__ void softmax_kernel(const float* __restrict__ sp, float* __restrict__ att) {
  const int b = blockIdx.x;
  const int tid = threadIdx.x;
  float* a = att + b * 2048;
  __shared__ float red[4];
  float mx = -1e30f;
  for (int l = tid; l < 2048; l += 256) {
    float v = 0.f;
#pragma unroll
    for (int g = 0; g < 8; ++g) v += sp[(size_t)g * 32768 + b * 2048 + l];
    a[l] = v;
    mx = fmaxf(mx, v);
  }
#pragma unroll
  for (int o = 1; o < 64; o <<= 1) mx = fmaxf(mx, __shfl_xor(mx, o));
  if ((tid & 63) == 0) red[tid >> 6] = mx;
  __syncthreads();
  mx = fmaxf(fmaxf(red[0], red[1]), fmaxf(red[2], red[3]));
  __syncthreads();
  float sum = 0.f;
  for (int l = tid; l < 2048; l += 256) {
    float e = __expf(a[l] - mx);
    a[l] = e;
    sum += e;
  }
#pragma unroll
  for (int o = 1; o < 64; o <<= 1) sum += __shfl_xor(sum, o);
  if ((tid & 63) == 0) red[tid >> 6] = sum;
  __syncthreads();
  sum = red[0] + red[1] + red[2] + red[3];
  const float inv = 1.0f / sum;
  for (int l = tid; l < 2048; l += 256) a[l] *= inv;
}

// ---------------- ctx_part[sl][b][j] = sum over 128 rows of att*keys (no atomics) ----------------
__global__ void ctxpre_kernel(const float* __restrict__ keys, const float* __restrict__ att,
                              float* __restrict__ ctx_part) {
  const int b = blockIdx.x;     // 16
  const int sl = blockIdx.y;    // 16 slices of 128 rows
  const int tid = threadIdx.x;  // 256
  const float* ab = att + b * 2048 + sl * 128;
  const f32x4* kp = (const f32x4*)(keys + ((size_t)b * 2048 + sl * 128) * 1024) + tid;
  f32x4 acc = {0.f, 0.f, 0.f, 0.f};
#pragma unroll 4
  for (int l = 0; l < 128; ++l) acc += kp[(size_t)l * 256] * ab[l];
  *(f32x4*)(ctx_part + ((size_t)(sl * 16 + b)) * 1024 + tid * 4) = acc;
}

// ---------------- ctx_pre[b][j] = sum_sl ctx_part[sl][b][j] ----------------
__global__ void ctxreduce_kernel(const float* __restrict__ ctx_part, float* __restrict__ ctx_pre) {
  const int i = blockIdx.x * 256 + threadIdx.x;  // 0..16383 = b*1024+j
  const int b = i >> 10, j = i & 1023;
  float s = 0.f;
#pragma unroll
  for (int sl = 0; sl < 16; ++sl) s += ctx_part[((size_t)(sl * 16 + b)) * 1024 + j];
  ctx_pre[i] = s;
}

// ---------------- context[b][h] = sum_j ctx_pre[b][j] * Wr[j][h] ----------------
__global__ void context_kernel(const float* __restrict__ ctx_pre, const float* __restrict__ Wr,
                               float* __restrict__ out) {
  const int b = blockIdx.y;
  const int h = blockIdx.x * 64 + (threadIdx.x & 63);
  const int jq = threadIdx.x >> 6;  // 0..3
  __shared__ float part[4][64];
  const float* cp = ctx_pre + b * 1024 + jq * 256;
  const float* wp = Wr + (size_t)(jq * 256) * 512 + h;
  float acc = 0.f;
#pragma unroll 8
  for (int k = 0; k < 256; ++k) acc += cp[k] * wp[(size_t)k * 512];
  part[jq][threadIdx.x & 63] = acc;
  __syncthreads();
  if (threadIdx.x < 64)
    out[b * 512 + blockIdx.x * 64 + threadIdx.x] = part[0][threadIdx.x] + part[1][threadIdx.x] +
                                                   part[2][threadIdx.x] + part[3][threadIdx.x];
}

extern "C" void kernel_launch(void* const* d_in, const int* in_sizes, int n_in, void* d_out,
                              int out_size, void* d_ws, size_t ws_size, hipStream_t stream) {
  const float* query = (const float*)d_in[0];     // (16,1,1024)
  const float* keys = (const float*)d_in[1];      // (16,2048,1024)
  const float* coverage = (const float*)d_in[2];  // (16,2048,1)
  const float* W1 = (const float*)d_in[3];        // (2049,1024)
  const float* b1 = (const float*)d_in[4];        // (1024,)
  const float* W2 = (const float*)d_in[5];        // (1024,1)
  const float* Wr = (const float*)d_in[6];        // (1024,512)
  float* out = (float*)d_out;
  char* ws = (char*)d_ws;

  float* scores_part = (float*)ws;          // 8*32768 f32 = 1MB @ 0
  float* ctx_part = (float*)ws;             // 16*16*1024 f32 = 1MB, ALIASES scores_part
                                            // (scores_part dead after softmax; serial stream)
  float* ctx_pre = (float*)(ws + 1048576);  // 16384 f32
  float* qterm = (float*)(ws + 1114112);    // 16384 f32
  unsigned short* W1kt = (unsigned short*)(ws + 1179648);  // 1M bf16 (2MB)

  float* context_out = out;     // 16*512
  float* att_out = out + 8192;  // 16*2048

  transpose_w1k<<<dim3(16, 16), dim3(256), 0, stream>>>(W1, W1kt);
  qterm_kernel<<<dim3(16, 16), dim3(256), 0, stream>>>(query, W1, b1, qterm);
  gemm_score_kernel<<<dim3(2048), dim3(256), 0, stream>>>(keys, W1kt, qterm, coverage, W1, W2,
                                                          scores_part);
  softmax_kernel<<<dim3(16), dim3(256), 0, stream>>>(scores_part, att_out);
  ctxpre_kernel<<<dim3(16, 16), dim3(256), 0, stream>>>(keys, att_out, ctx_part);
  ctxreduce_kernel<<<dim3(64), dim3(256), 0, stream>>>(ctx_part, ctx_pre);
  context_kernel<<<dim3(8, 16), dim3(256), 0, stream>>>(ctx_pre, Wr, context_out);
}